// Round 4
// baseline (245.835 us; speedup 1.0000x reference)
//
#include <hip/hip_runtime.h>

// Stride-2 3x3 conv as implicit GEMM, f16 MFMA 32x32x16.
// Round 4 = Round 3 structure with the weight-repack axis-order bug fixed:
// repack unit decode now matches the consumer layout [cc][khw][h][co_l][ci8].
// m97-style single-buffered 2-barrier K-loop, 2 blocks/CU (8 waves/CU),
// block tile 128co x 128n (4 oh rows), wave tile 64x64.
// x staged with wide float4 loads (9/thread/chunk), ds_write_b64 scatter into
// plane-split LDS; weights via global_load_lds 16B DMA.

#define CIN  256
#define H_   64
#define W_   64
#define OH   32
#define OW   32
#define HW   4096

typedef _Float16 f16;
typedef _Float16 half8 __attribute__((ext_vector_type(8)));
typedef _Float16 half4 __attribute__((ext_vector_type(4)));
typedef float    f32x4 __attribute__((ext_vector_type(4)));
typedef float    floatx16 __attribute__((ext_vector_type(16)));

typedef const __attribute__((address_space(1))) void g_void;
typedef __attribute__((address_space(3))) void l_void;

// rp layout: [co_t 2][cc 16][khw 9][h 2][co_l 128][ci8 8] f16
// unit index o = ((((co_t*16+cc)*9 + khw)*2 + h)*128 + co_l)
__global__ __launch_bounds__(256) void repack_w_kernel(const float* __restrict__ w,
                                                       f16* __restrict__ rp) {
  int o = blockIdx.x * 256 + threadIdx.x;   // 73728 units total, exact
  int co_l = o & 127;
  int t2   = o >> 7;
  int h    = t2 & 1;
  int t3   = t2 >> 1;
  int khw  = t3 % 9;
  int t4   = t3 / 9;
  int cc   = t4 & 15;
  int co_t = t4 >> 4;
  int co  = co_t * 128 + co_l;
  int ci0 = cc * 16 + h * 8;
  half8 v;
#pragma unroll
  for (int j = 0; j < 8; ++j) v[j] = (f16)w[(co * CIN + ci0 + j) * 9 + khw];
  *(half8*)(rp + (size_t)o * 8) = v;
}

__global__ __launch_bounds__(256, 2) void conv_mfma_kernel(
    const float* __restrict__ x, const f16* __restrict__ rp,
    float* __restrict__ out) {
  // weights chunk: [khw 9][h 2][co 128][8] f16 = 36864 B
  __shared__ f16 ws[9 * 2 * 128 * 8];
  // x chunk, plane-split: cell(r,p,h,idx) -> [((r*2+p)*2+h)][idx 33][8] = 19008 B
  __shared__ f16 xs[9 * 2 * 2 * 33 * 8];

  const int t    = threadIdx.x;
  const int lane = t & 63;
  const int wave = t >> 6;
  const int h    = lane >> 5;    // k-half
  const int ml   = lane & 31;
  const int wm   = wave >> 1;    // co 64-half
  const int wn   = wave & 1;     // n 64-half (= 2 oh rows of the block's 4)

  const int blk  = blockIdx.x;   // 512 = b*16 + ohg*2 + co_t
  const int co_t = blk & 1;
  const int ohg  = (blk >> 1) & 7;
  const int b    = blk >> 4;
  const int oh0  = ohg * 4;
  const int ih0  = 2 * oh0 - 1;

  const float* xb  = x  + (size_t)b * CIN * HW;
  const f16*   rpb = rp + (size_t)co_t * (16 * 18432);

  // zero the left-pad cells (odd plane, idx 0) once; staging never writes them
  if (t < 18) {
    int r = t >> 1, hh = t & 1;
    half8 z = {};
    *(half8*)&xs[(((r * 2 + 1) * 2 + hh) * 33 + 0) * 8] = z;
  }

  floatx16 acc[2][2];
#pragma unroll
  for (int mi = 0; mi < 2; ++mi)
#pragma unroll
    for (int nj = 0; nj < 2; ++nj)
#pragma unroll
      for (int i = 0; i < 16; ++i) acc[mi][nj][i] = 0.f;

  for (int cc = 0; cc < 16; ++cc) {
    __syncthreads();
    // ---- weights: global -> LDS DMA, 36 x 1KB wave-instructions ----
    {
      const char* src = (const char*)rpb + (size_t)cc * 36864 + wave * 9216 + lane * 16;
      char* dst = (char*)ws + wave * 9216 + lane * 16;
#pragma unroll
      for (int i = 0; i < 9; ++i)
        __builtin_amdgcn_global_load_lds((g_void*)(src + i * 1024),
                                         (l_void*)(dst + i * 1024), 16, 0, 0);
    }
    // ---- x: 576 units of (4 ci rows x 4 iw), float4 loads + b64 scatter ----
#pragma unroll
    for (int it = 0; it < 3; ++it) {
      int u = t + it * 256;
      if (u < 576) {
        int iwq = u & 15;
        int rg  = u >> 4;          // 0..35
        int r   = rg % 9;
        int g   = rg / 9;          // ci quad 0..3
        int ih  = ih0 + r;
        int ihc = ih < 0 ? 0 : ih;
        const float* bp = xb + (size_t)(cc * 16 + g * 4) * HW + (size_t)ihc * W_ + iwq * 4;
        f32x4 v0 = *(const f32x4*)(bp);
        f32x4 v1 = *(const f32x4*)(bp + HW);
        f32x4 v2 = *(const f32x4*)(bp + 2 * HW);
        f32x4 v3 = *(const f32x4*)(bp + 3 * HW);
        if (ih < 0) {
          f32x4 z = {0.f, 0.f, 0.f, 0.f};
          v0 = z; v1 = z; v2 = z; v3 = z;
        }
        const int hh  = g >> 1;
        const int sub = (g & 1) * 4;
#pragma unroll
        for (int o = 0; o < 4; ++o) {
          int iw  = iwq * 4 + o;
          int p   = iw & 1;
          int idx = (iw + p) >> 1;
          half4 d;
          d[0] = (f16)v0[o];
          d[1] = (f16)v1[o];
          d[2] = (f16)v2[o];
          d[3] = (f16)v3[o];
          *(half4*)&xs[(((r * 2 + p) * 2 + hh) * 33 + idx) * 8 + sub] = d;
        }
      }
    }
    __syncthreads();

    // ---- compute: 9 taps x (2 A-frags + 2 B-frags + 4 MFMA) per wave ----
#pragma unroll
    for (int kh = 0; kh < 3; ++kh) {
#pragma unroll
      for (int kw = 0; kw < 3; ++kw) {
        const int khw = kh * 3 + kw;
        half8 a0 = *(const half8*)&ws[((khw * 2 + h) * 128 + wm * 64 + ml) * 8];
        half8 a1 = *(const half8*)&ws[((khw * 2 + h) * 128 + wm * 64 + 32 + ml) * 8];
        const int pp = (kw & 1) ^ 1;       // kw=1 -> even plane
        const int ix = ml + (kw >> 1);
#pragma unroll
        for (int nj = 0; nj < 2; ++nj) {
          const int r = 2 * (wn * 2 + nj) + kh;
          half8 bf = *(const half8*)&xs[(((r * 2 + pp) * 2 + h) * 33 + ix) * 8];
          acc[0][nj] = __builtin_amdgcn_mfma_f32_32x32x16_f16(a0, bf, acc[0][nj], 0, 0, 0);
          acc[1][nj] = __builtin_amdgcn_mfma_f32_32x32x16_f16(a1, bf, acc[1][nj], 0, 0, 0);
        }
      }
    }
  }

  // ---- epilogue: C/D col = lane&31 (=ow), row = (reg&3)+8*(reg>>2)+4*(lane>>5) ----
  float* ob = out + ((size_t)b * 256 + co_t * 128 + wm * 64) * (OH * OW);
  const int rb4 = h * 4;
#pragma unroll
  for (int mi = 0; mi < 2; ++mi) {
#pragma unroll
    for (int nj = 0; nj < 2; ++nj) {
      const int oh = oh0 + wn * 2 + nj;
#pragma unroll
      for (int r = 0; r < 16; ++r) {
        const int row = mi * 32 + (r & 3) + 8 * (r >> 2) + rb4;
        ob[(size_t)row * (OH * OW) + oh * OW + ml] = acc[mi][nj][r];
      }
    }
  }
}

extern "C" void kernel_launch(void* const* d_in, const int* in_sizes, int n_in,
                              void* d_out, int out_size, void* d_ws, size_t ws_size,
                              hipStream_t stream) {
  const float* x = (const float*)d_in[0];   // [32][256][64][64] fp32
  const float* w = (const float*)d_in[1];   // [256][256][3][3]  fp32
  float* out = (float*)d_out;               // [32][256][32][32] fp32
  f16* rp = (f16*)d_ws;                     // 1.18 MB repacked f16 weights

  repack_w_kernel<<<288, 256, 0, stream>>>(w, rp);
  conv_mfma_kernel<<<512, 256, 0, stream>>>(x, rp, out);
}